// Round 1
// baseline (1308.756 us; speedup 1.0000x reference)
//
#include <hip/hip_runtime.h>

// IntegratedNCA: 10 steps of {sobel-perceive -> MLP(112->128->16) -> residual -> life gate}
// B=16, C=16, H=W=128, WDIM=64, HID=128.
// Strategy:
//  - Fold w-part of Linear1 + b1 into a per-batch bias (constant across steps/pixels).
//  - Per-step kernel: 16x16 pixel tile per 256-thread block, 18x18x16ch LDS halo.
//  - One thread = one pixel; hidden dim in 8 chunks of 16 to bound VGPRs.
//  - Weights read at wave-uniform indices -> scalar (SGPR) loads, no LDS for weights.
//  - Ping-pong x between d_ws and d_out so final step writes d_out.

#define CCH   16
#define WDIM  64
#define HID   128
#define BATCH 16
#define HH    128
#define WWID  128
#define KIN   48           // 3*C
#define NIN   112          // 3*C + WDIM
#define TS    16
#define HALO  18
#define STEPS 10

__global__ __launch_bounds__(128) void nca_bias_kernel(
    const float* __restrict__ W1, const float* __restrict__ b1,
    const float* __restrict__ w, float* __restrict__ biasw)
{
    int n = threadIdx.x;     // hidden unit 0..127
    int b = blockIdx.x;      // batch 0..15
    float acc = b1[n];
    const float* wrow  = w  + b * WDIM;
    const float* W1row = W1 + n * NIN + KIN;   // w-part of row n
    #pragma unroll
    for (int j = 0; j < WDIM; ++j) acc = fmaf(W1row[j], wrow[j], acc);
    biasw[b * HID + n] = acc;
}

__global__ __launch_bounds__(256) void nca_step_kernel(
    const float* __restrict__ xin, float* __restrict__ xout,
    const float* __restrict__ W1, const float* __restrict__ W2,
    const float* __restrict__ b2, const float* __restrict__ biasw)
{
    __shared__ float tile[CCH][HALO][HALO];

    const int b   = blockIdx.z;
    const int ty0 = blockIdx.y * TS;
    const int tx0 = blockIdx.x * TS;
    const int tid = threadIdx.x;

    // ---- stage x tile + halo (zero-padded; safe for both conv and life-maxpool) ----
    const float* xb = xin + b * CCH * HH * WWID;
    for (int idx = tid; idx < CCH * HALO * HALO; idx += 256) {
        int c  = idx / (HALO * HALO);
        int r  = idx % (HALO * HALO);
        int ly = r / HALO, lx = r % HALO;
        int gy = ty0 + ly - 1, gx = tx0 + lx - 1;
        float v = 0.f;
        if (gy >= 0 && gy < HH && gx >= 0 && gx < WWID)
            v = xb[c * HH * WWID + gy * WWID + gx];
        tile[c][ly][lx] = v;
    }
    __syncthreads();

    const int ty = tid >> 4, tx = tid & 15;
    const int ly = ty + 1,  lx = tx + 1;

    // ---- build inp[48] = [x, gx, gy] and pre_life (maxpool3 of ch3 > 0.1) ----
    float inp[KIN];
    bool pre_life = false;
    #pragma unroll
    for (int c = 0; c < CCH; ++c) {
        float x_mm = tile[c][ly-1][lx-1], x_m0 = tile[c][ly-1][lx], x_mp = tile[c][ly-1][lx+1];
        float x_0m = tile[c][ly  ][lx-1], x_00 = tile[c][ly  ][lx], x_0p = tile[c][ly  ][lx+1];
        float x_pm = tile[c][ly+1][lx-1], x_p0 = tile[c][ly+1][lx], x_pp = tile[c][ly+1][lx+1];
        inp[c] = x_00;
        // cross-correlation (XLA/torch conv semantics, no kernel flip)
        inp[CCH   + c] = (x_mp - x_mm) + 2.f * (x_0p - x_0m) + (x_pp - x_pm);  // sobel_x
        inp[2*CCH + c] = (x_pm - x_mm) + 2.f * (x_p0 - x_m0) + (x_pp - x_mp);  // sobel_y
        if (c == 3) {
            float m = fmaxf(fmaxf(fmaxf(x_mm, x_m0), fmaxf(x_mp, x_0m)),
                            fmaxf(fmaxf(x_00, x_0p), fmaxf(x_pm, fmaxf(x_p0, x_pp))));
            pre_life = (m > 0.1f);
        }
    }

    // ---- MLP: hdd = relu(W1x*inp + biasw[b]); ds = W2*hdd + b2 ----
    float ds[CCH];
    #pragma unroll
    for (int c = 0; c < CCH; ++c) ds[c] = b2[c];

    const float* biasb = biasw + b * HID;
    #pragma unroll 1                     // keep loop body I-cache resident
    for (int h0 = 0; h0 < HID; h0 += 16) {
        float hh[16];
        #pragma unroll
        for (int n = 0; n < 16; ++n) hh[n] = biasb[h0 + n];      // uniform -> s_load
        #pragma unroll
        for (int k = 0; k < KIN; ++k) {
            float iv = inp[k];
            #pragma unroll
            for (int n = 0; n < 16; ++n)
                hh[n] = fmaf(iv, W1[(h0 + n) * NIN + k], hh[n]); // W1: uniform -> s_load
        }
        #pragma unroll
        for (int n = 0; n < 16; ++n) hh[n] = fmaxf(hh[n], 0.f);
        #pragma unroll
        for (int n = 0; n < 16; ++n) {
            float hv = hh[n];
            #pragma unroll
            for (int c = 0; c < CCH; ++c)
                ds[c] = fmaf(hv, W2[c * HID + h0 + n], ds[c]);   // W2: uniform -> s_load
        }
    }

    // ---- residual + life gate, store ----
    float new3  = inp[3] + ds[3];
    float alive = ((new3 > 0.1f) && pre_life) ? 1.f : 0.f;
    float* ob = xout + b * CCH * HH * WWID;
    const int gy = ty0 + ty, gx = tx0 + tx;
    #pragma unroll
    for (int c = 0; c < CCH; ++c) {
        float nv = inp[c] + ds[c];
        ob[c * HH * WWID + gy * WWID + gx] = nv * alive;
    }
}

extern "C" void kernel_launch(void* const* d_in, const int* in_sizes, int n_in,
                              void* d_out, int out_size, void* d_ws, size_t ws_size,
                              hipStream_t stream) {
    const float* x   = (const float*)d_in[0];
    const float* w   = (const float*)d_in[1];
    const float* W1  = (const float*)d_in[2];
    const float* b1  = (const float*)d_in[3];
    const float* W2  = (const float*)d_in[4];
    const float* b2  = (const float*)d_in[5];
    // d_in[6], d_in[7]: sobel kernels (fixed values, hard-coded); d_in[8]: steps (=10)
    float* out = (float*)d_out;

    float* ws0   = (float*)d_ws;                       // 16 MB ping-pong buffer
    float* biasw = ws0 + BATCH * CCH * HH * WWID;      // 2048 floats

    nca_bias_kernel<<<BATCH, HID, 0, stream>>>(W1, b1, w, biasw);

    dim3 grid(WWID / TS, HH / TS, BATCH);
    for (int s = 0; s < STEPS; ++s) {
        // dst alternates so that step STEPS-1 writes d_out
        float* dst = (((STEPS - 1 - s) & 1) == 0) ? out : ws0;
        const float* src = (s == 0) ? x
                         : ((((STEPS - s) & 1) == 0) ? (const float*)out : (const float*)ws0);
        nca_step_kernel<<<grid, 256, 0, stream>>>(src, dst, W1, W2, b2, biasw);
    }
}

// Round 2
// 781.858 us; speedup vs baseline: 1.6739x; 1.6739x over previous
//
#include <hip/hip_runtime.h>

// IntegratedNCA: 10 steps of {sobel-perceive -> MLP(112->128->16) -> residual -> life gate}
// B=16, C=16, H=W=128, WDIM=64, HID=128.
// R2 changes vs R1:
//  - __launch_bounds__(256,2): R1's VGPR=52 forced inp[48] to scratch (FETCH 29MB vs 17MB ideal).
//  - Weights pre-transposed to W1t[k][n], W2t[n][c]: contiguous 16-float runs at wave-uniform
//    addresses -> s_load_dwordx8 batches instead of 16 scattered cache lines per k.

#define CCH   16
#define WDIM  64
#define HID   128
#define BATCH 16
#define HH    128
#define WWID  128
#define KIN   48           // 3*C
#define NIN   112          // 3*C + WDIM
#define TS    16
#define HALO  18
#define STEPS 10

// One small prep kernel: per-batch folded bias + weight transposes.
__global__ __launch_bounds__(256) void nca_prep_kernel(
    const float* __restrict__ W1, const float* __restrict__ b1,
    const float* __restrict__ w,  const float* __restrict__ W2,
    float* __restrict__ biasw, float* __restrict__ W1t, float* __restrict__ W2t)
{
    const int t = threadIdx.x;
    // W1t[k][n] = W1[n][k]   (48 x 128)
    for (int i = t; i < KIN * HID; i += 256) {
        int k = i / HID, n = i % HID;
        W1t[k * HID + n] = W1[n * NIN + k];
    }
    // W2t[n][c] = W2[c][n]   (128 x 16)
    for (int i = t; i < HID * CCH; i += 256) {
        int n = i / CCH, c = i % CCH;
        W2t[n * CCH + c] = W2[c * HID + n];
    }
    // biasw[b][n] = b1[n] + sum_j W1[n][48+j] * w[b][j]
    for (int i = t; i < BATCH * HID; i += 256) {
        int b = i / HID, n = i % HID;
        float acc = b1[n];
        const float* wrow  = w  + b * WDIM;
        const float* W1row = W1 + n * NIN + KIN;
        #pragma unroll
        for (int j = 0; j < WDIM; ++j) acc = fmaf(W1row[j], wrow[j], acc);
        biasw[i] = acc;
    }
}

__global__ __launch_bounds__(256, 2) void nca_step_kernel(
    const float* __restrict__ xin, float* __restrict__ xout,
    const float* __restrict__ W1t, const float* __restrict__ W2t,
    const float* __restrict__ b2, const float* __restrict__ biasw)
{
    __shared__ float tile[CCH][HALO][HALO];

    const int b   = blockIdx.z;
    const int ty0 = blockIdx.y * TS;
    const int tx0 = blockIdx.x * TS;
    const int tid = threadIdx.x;

    // ---- stage x tile + halo (zero-padded; safe for both conv and life-maxpool) ----
    const float* xb = xin + b * CCH * HH * WWID;
    for (int idx = tid; idx < CCH * HALO * HALO; idx += 256) {
        int c  = idx / (HALO * HALO);
        int r  = idx % (HALO * HALO);
        int ly = r / HALO, lx = r % HALO;
        int gy = ty0 + ly - 1, gx = tx0 + lx - 1;
        float v = 0.f;
        if (gy >= 0 && gy < HH && gx >= 0 && gx < WWID)
            v = xb[c * HH * WWID + gy * WWID + gx];
        tile[c][ly][lx] = v;
    }
    __syncthreads();

    const int ty = tid >> 4, tx = tid & 15;
    const int ly = ty + 1,  lx = tx + 1;

    // ---- build inp[48] = [x, gx, gy] and pre_life (maxpool3 of ch3 > 0.1) ----
    float inp[KIN];
    bool pre_life = false;
    #pragma unroll
    for (int c = 0; c < CCH; ++c) {
        float x_mm = tile[c][ly-1][lx-1], x_m0 = tile[c][ly-1][lx], x_mp = tile[c][ly-1][lx+1];
        float x_0m = tile[c][ly  ][lx-1], x_00 = tile[c][ly  ][lx], x_0p = tile[c][ly  ][lx+1];
        float x_pm = tile[c][ly+1][lx-1], x_p0 = tile[c][ly+1][lx], x_pp = tile[c][ly+1][lx+1];
        inp[c] = x_00;
        // cross-correlation (XLA conv semantics, no kernel flip)
        inp[CCH   + c] = (x_mp - x_mm) + 2.f * (x_0p - x_0m) + (x_pp - x_pm);  // sobel_x
        inp[2*CCH + c] = (x_pm - x_mm) + 2.f * (x_p0 - x_m0) + (x_pp - x_mp);  // sobel_y
        if (c == 3) {
            float m = fmaxf(fmaxf(fmaxf(x_mm, x_m0), fmaxf(x_mp, x_0m)),
                            fmaxf(fmaxf(x_00, x_0p), fmaxf(x_pm, fmaxf(x_p0, x_pp))));
            pre_life = (m > 0.1f);
        }
    }

    // ---- MLP: hdd = relu(W1t^T inp + biasw[b]); ds = W2t^T hdd + b2 ----
    float ds[CCH];
    #pragma unroll
    for (int c = 0; c < CCH; ++c) ds[c] = b2[c];

    const float* biasb = biasw + b * HID;
    #pragma unroll 1                     // keep loop body I-cache resident
    for (int h0 = 0; h0 < HID; h0 += 16) {
        float hh[16];
        #pragma unroll
        for (int n = 0; n < 16; ++n) hh[n] = biasb[h0 + n];        // uniform -> s_load
        #pragma unroll
        for (int k = 0; k < KIN; ++k) {
            float iv = inp[k];
            const float* wrow = W1t + k * HID + h0;                // uniform, contiguous 16
            #pragma unroll
            for (int n = 0; n < 16; ++n)
                hh[n] = fmaf(iv, wrow[n], hh[n]);
        }
        #pragma unroll
        for (int n = 0; n < 16; ++n) hh[n] = fmaxf(hh[n], 0.f);
        #pragma unroll
        for (int n = 0; n < 16; ++n) {
            float hv = hh[n];
            const float* w2row = W2t + (h0 + n) * CCH;             // uniform, contiguous 16
            #pragma unroll
            for (int c = 0; c < CCH; ++c)
                ds[c] = fmaf(hv, w2row[c], ds[c]);
        }
    }

    // ---- residual + life gate, store ----
    float new3  = inp[3] + ds[3];
    float alive = ((new3 > 0.1f) && pre_life) ? 1.f : 0.f;
    float* ob = xout + b * CCH * HH * WWID;
    const int gy = ty0 + ty, gx = tx0 + tx;
    #pragma unroll
    for (int c = 0; c < CCH; ++c) {
        float nv = inp[c] + ds[c];
        ob[c * HH * WWID + gy * WWID + gx] = nv * alive;
    }
}

extern "C" void kernel_launch(void* const* d_in, const int* in_sizes, int n_in,
                              void* d_out, int out_size, void* d_ws, size_t ws_size,
                              hipStream_t stream) {
    const float* x   = (const float*)d_in[0];
    const float* w   = (const float*)d_in[1];
    const float* W1  = (const float*)d_in[2];
    const float* b1  = (const float*)d_in[3];
    const float* W2  = (const float*)d_in[4];
    const float* b2  = (const float*)d_in[5];
    // d_in[6], d_in[7]: sobel kernels (fixed values, hard-coded); d_in[8]: steps (=10)
    float* out = (float*)d_out;

    float* ws0   = (float*)d_ws;                       // 16 MB ping-pong buffer
    float* biasw = ws0 + BATCH * CCH * HH * WWID;      // 2048 floats
    float* W1t   = biasw + BATCH * HID;                // 6144 floats
    float* W2t   = W1t + KIN * HID;                    // 2048 floats

    nca_prep_kernel<<<1, 256, 0, stream>>>(W1, b1, w, W2, biasw, W1t, W2t);

    dim3 grid(WWID / TS, HH / TS, BATCH);
    for (int s = 0; s < STEPS; ++s) {
        // dst alternates so that step STEPS-1 writes d_out
        float* dst = (((STEPS - 1 - s) & 1) == 0) ? out : ws0;
        const float* src = (s == 0) ? x
                         : ((((STEPS - s) & 1) == 0) ? (const float*)out : (const float*)ws0);
        nca_step_kernel<<<grid, 256, 0, stream>>>(src, dst, W1t, W2t, b2, biasw);
    }
}